// Round 9
// baseline (102.006 us; speedup 1.0000x reference)
//
#include <hip/hip_runtime.h>

#define N_NODES 10000
#define N_EDGES 160000
#define M_PAD   10112   // 79 * 128
#define MT      79
#define KT      8       // K = 512 = 8 * 64
#define ELLW    64      // max degree slot count (Poisson(16) tail @64 ~ 1e-18)

typedef short s8v __attribute__((ext_vector_type(8)));
typedef short s4v __attribute__((ext_vector_type(4)));
typedef float f4v __attribute__((ext_vector_type(4)));

__device__ inline short f2bf(float f) {
    unsigned u = __builtin_bit_cast(unsigned, f);
    u += 0x7FFF + ((u >> 16) & 1);   // RTNE
    return (short)(u >> 16);
}
__device__ inline float bf2f(short s) {
    return __builtin_bit_cast(float, ((unsigned)(unsigned short)s) << 16);
}

#define GLD_LDS16(g, l)                                                      \
    __builtin_amdgcn_global_load_lds(                                        \
        (const __attribute__((address_space(1))) unsigned int*)(g),          \
        (__attribute__((address_space(3))) unsigned int*)(l), 16, 0, 0)

// ---------------------------------------------------------------------------
// k_prep: W conversions + deg/count init (x conversion now lives in gemm1).
//   [0, 128)   : W1^T -> bf16 tiled (512 cols)
//   [128, 192) : W2^T -> bf16 tiled (256 cols)
//   [192, 232) : deg = 1.0, count = 0
// Tile image = 16 KiB: [128 rows][64 k] bf16; chunk (r, slot) holds
// k = (slot ^ (r&7))*8 .. +8.  Buffer: [row_tile][k_tile][16384 B].
// ---------------------------------------------------------------------------
__global__ __launch_bounds__(256) void k_prep(const float* __restrict__ W1,
                                              const float* __restrict__ W2,
                                              char* __restrict__ w1T,
                                              char* __restrict__ w2T,
                                              float* __restrict__ deg,
                                              int* __restrict__ count) {
    int bid = blockIdx.x;
    if (bid < 192) {
        const float* W;
        char* out;
        int ncols, t;
        if (bid < 128) { W = W1; out = w1T; ncols = 512; t = bid * 256 + threadIdx.x; }
        else           { W = W2; out = w2T; ncols = 256; t = (bid - 128) * 256 + threadIdx.x; }
        int n = t >> 6;
        int c = t & 63;
        s8v v;
#pragma unroll
        for (int j = 0; j < 8; j++) v[j] = f2bf(W[(long long)(c * 8 + j) * ncols + n]);
        int r = n & 127, tn = n >> 7, tk = c >> 3, sc = c & 7;
        int slot = sc ^ (r & 7);
        *(s8v*)&out[(((long long)tn * KT + tk) << 14) + r * 128 + slot * 16] = v;
    } else {
        int i = (bid - 192) * 256 + threadIdx.x;
        if (i < N_NODES) { deg[i] = 1.0f; count[i] = 0; }
    }
}

// ---------------------------------------------------------------------------
// XCD-chunked (by,bx) mapping over 320 virtual blocks (8 xcd x 10 by x 4 bx):
// all 4 bx-siblings of a by land on ONE xcd (blockIdx % 8 assumed = xcd).
// by = (b&7)*10 + (b>>3)/4, bx = (b>>3)&3; by==79 -> idle.
// ---------------------------------------------------------------------------
__device__ __forceinline__ void xcd_map(int b, int& by, int& bx) {
    by = (b & 7) * 10 + ((b >> 3) >> 2);
    bx = (b >> 3) & 3;
}

// ---------------------------------------------------------------------------
// layer-1 GEMM, 128x128 tile, BK=64, inline x fp32->bf16 A-staging,
// + fused {deg accumulate, ELL fill} edge pass (blocks >= 320).
// ---------------------------------------------------------------------------
__global__ __launch_bounds__(256) void k_gemm1_deg(const float* __restrict__ x,
                                                   const char* __restrict__ w1T,
                                                   short* __restrict__ Cb,
                                                   const int* __restrict__ src,
                                                   const int* __restrict__ dst,
                                                   const float* __restrict__ wgt,
                                                   float* __restrict__ deg,
                                                   int* __restrict__ count,
                                                   int2* __restrict__ ell) {
    int bid = blockIdx.x;
    if (bid >= 320) {
        int e = (bid - 320) * 256 + threadIdx.x;
        if (e < N_EDGES) {
            int d = dst[e];
            float wv = wgt[e];
            atomicAdd(&deg[d], wv);
            int pos = atomicAdd(&count[d], 1);
            if (pos < ELLW)
                ell[(long long)d * ELLW + pos] = make_int2(src[e], __float_as_int(wv));
        }
        return;
    }
    int by, bx;
    xcd_map(bid, by, bx);
    if (by >= MT) return;

    __shared__ char As[16384];
    __shared__ char Bs[16384];
    int tid = threadIdx.x, lane = tid & 63, w = tid >> 6;
    int wr = w >> 1, wc = w & 1;

    const char* gb = w1T + ((long long)bx * KT << 14);

    f4v acc[4][4];
#pragma unroll
    for (int m = 0; m < 4; m++)
#pragma unroll
        for (int n = 0; n < 4; n++) acc[m][n] = (f4v){0.f, 0.f, 0.f, 0.f};

    for (int kt = 0; kt < KT; ++kt) {
        // ---- A: reg-stage x fp32 -> bf16 swizzled LDS (128 rows x 64 k) ----
        // chunk c = it*256 + tid: row = c>>4, f4 = c&15 (16 float4 per row)
#pragma unroll
        for (int it = 0; it < 8; ++it) {
            int c = it * 256 + tid;
            int r = c >> 4, f4 = c & 15;
            int gr = by * 128 + r;
            float4 v = make_float4(0.f, 0.f, 0.f, 0.f);
            if (gr < N_NODES) v = *(const float4*)&x[(long long)gr * 512 + kt * 64 + f4 * 4];
            s4v b;
            b[0] = f2bf(v.x); b[1] = f2bf(v.y); b[2] = f2bf(v.z); b[3] = f2bf(v.w);
            int slot = (f4 >> 1) ^ (r & 7);
            *(s4v*)&As[r * 128 + slot * 16 + (f4 & 1) * 8] = b;
        }
        // ---- B: global_load_lds from tiled w1T ----
        const char* b0 = gb + (kt << 14);
#pragma unroll
        for (int j = 0; j < 4; ++j) {
            int off = (j * 256 + w * 64) * 16;
            GLD_LDS16(b0 + off + lane * 16, Bs + off);
        }
        __syncthreads();

#pragma unroll
        for (int kk = 0; kk < 2; ++kk) {
            s8v a[4], b[4];
#pragma unroll
            for (int m = 0; m < 4; ++m) {
                int r = wr * 64 + m * 16 + (lane & 15);
                int slot = ((lane >> 4) + kk * 4) ^ (r & 7);
                a[m] = *(const s8v*)&As[r * 128 + slot * 16];
            }
#pragma unroll
            for (int n = 0; n < 4; ++n) {
                int r = wc * 64 + n * 16 + (lane & 15);
                int slot = ((lane >> 4) + kk * 4) ^ (r & 7);
                b[n] = *(const s8v*)&Bs[r * 128 + slot * 16];
            }
#pragma unroll
            for (int m = 0; m < 4; ++m)
#pragma unroll
                for (int n = 0; n < 4; ++n)
                    acc[m][n] = __builtin_amdgcn_mfma_f32_16x16x32_bf16(a[m], b[n], acc[m][n], 0, 0, 0);
        }
        __syncthreads();
    }

    int row0 = by * 128 + wr * 64;
    int col0 = bx * 128 + wc * 64;
#pragma unroll
    for (int m = 0; m < 4; ++m) {
#pragma unroll
        for (int q = 0; q < 4; ++q) {
            int row = row0 + m * 16 + (lane >> 4) * 4 + q;
            if (row < N_NODES) {
#pragma unroll
                for (int n = 0; n < 4; ++n) {
                    int col = col0 + n * 16 + (lane & 15);
                    Cb[(long long)row * 512 + col] = f2bf(acc[m][n][q]);
                }
            }
        }
    }
}

// ---------------------------------------------------------------------------
// layer-2 GEMM: 128(M) x 64(N) tile, A from tiled a1_bf images, B from w2T
// half-images (8 KiB). 4 waves as 2x2, wave tile 64x32. XCD-chunked mapping.
// ---------------------------------------------------------------------------
__global__ __launch_bounds__(256) void k_gemm2(const char* __restrict__ A,
                                               const char* __restrict__ w2T,
                                               short* __restrict__ Cb) {
    int by, bx;
    xcd_map(blockIdx.x, by, bx);
    if (by >= MT) return;

    __shared__ char As[16384];
    __shared__ char Bs[8192];
    int tid = threadIdx.x, lane = tid & 63, w = tid >> 6;
    int wr = w >> 1, wc = w & 1;

    const char* ga = A + ((long long)by * KT << 14);
    const char* gbase = w2T + ((long long)(bx >> 1) * KT << 14) + (bx & 1) * 8192;

    f4v acc[4][2];
#pragma unroll
    for (int m = 0; m < 4; m++)
#pragma unroll
        for (int n = 0; n < 2; n++) acc[m][n] = (f4v){0.f, 0.f, 0.f, 0.f};

    for (int kt = 0; kt < KT; ++kt) {
        const char* a0 = ga + (kt << 14);
        const char* b0 = gbase + (kt << 14);
#pragma unroll
        for (int j = 0; j < 4; ++j) {
            int off = (j * 256 + w * 64) * 16;
            GLD_LDS16(a0 + off + lane * 16, As + off);
        }
#pragma unroll
        for (int j = 0; j < 2; ++j) {
            int off = (j * 256 + w * 64) * 16;
            GLD_LDS16(b0 + off + lane * 16, Bs + off);
        }
        __syncthreads();

#pragma unroll
        for (int kk = 0; kk < 2; ++kk) {
            s8v a[4], b[2];
#pragma unroll
            for (int m = 0; m < 4; ++m) {
                int r = wr * 64 + m * 16 + (lane & 15);
                int slot = ((lane >> 4) + kk * 4) ^ (r & 7);
                a[m] = *(const s8v*)&As[r * 128 + slot * 16];
            }
#pragma unroll
            for (int n = 0; n < 2; ++n) {
                int r = wc * 32 + n * 16 + (lane & 15);
                int slot = ((lane >> 4) + kk * 4) ^ (r & 7);
                b[n] = *(const s8v*)&Bs[r * 128 + slot * 16];
            }
#pragma unroll
            for (int m = 0; m < 4; ++m)
#pragma unroll
                for (int n = 0; n < 2; ++n)
                    acc[m][n] = __builtin_amdgcn_mfma_f32_16x16x32_bf16(a[m], b[n], acc[m][n], 0, 0, 0);
        }
        __syncthreads();
    }

    int row0 = by * 128 + wr * 64;
    int col0 = bx * 64 + wc * 32;
#pragma unroll
    for (int m = 0; m < 4; ++m) {
#pragma unroll
        for (int q = 0; q < 4; ++q) {
            int row = row0 + m * 16 + (lane >> 4) * 4 + q;
            if (row < N_NODES) {
#pragma unroll
                for (int n = 0; n < 2; ++n) {
                    int col = col0 + n * 16 + (lane & 15);
                    Cb[(long long)row * 256 + col] = f2bf(acc[m][n][q]);
                }
            }
        }
    }
}

// ---------------------------------------------------------------------------
// ELL gather aggregation, bf16 input, norm computed in-flight.
// One wave per node, 4-edge unroll.
// ---------------------------------------------------------------------------
template <int F, bool RELU, bool OUT_TILED>
__global__ __launch_bounds__(256) void k_gather(const int2* __restrict__ ell,
                                                const int* __restrict__ count,
                                                const short* __restrict__ hb,
                                                const float* __restrict__ deg,
                                                void* __restrict__ outp,
                                                int n_waves) {
    const int FPT = F / 64;  // 8 (F=512) or 4 (F=256)
    int wave = (int)((blockIdx.x * (long long)blockDim.x + threadIdx.x) >> 6);
    if (wave >= n_waves) return;
    int lane = threadIdx.x & 63;

    float acc[FPT];
#pragma unroll
    for (int j = 0; j < FPT; j++) acc[j] = 0.f;

    if (wave < N_NODES) {
        float dg = deg[wave];
        float inv = 1.0f / dg;
        float dinv_d = rsqrtf(dg);
        {
            if constexpr (FPT == 8) {
                s8v v = *(const s8v*)&hb[(long long)wave * F + lane * 8];
#pragma unroll
                for (int j = 0; j < 8; j++) acc[j] = bf2f(v[j]) * inv;
            } else {
                s4v v = *(const s4v*)&hb[(long long)wave * F + lane * 4];
#pragma unroll
                for (int j = 0; j < 4; j++) acc[j] = bf2f(v[j]) * inv;
            }
        }
        int cnt = count[wave];
        if (cnt > ELLW) cnt = ELLW;
        const int2* row = &ell[(long long)wave * ELLW];
        int p = 0;
        for (; p + 3 < cnt; p += 4) {
            int2 e0 = row[p], e1 = row[p + 1], e2 = row[p + 2], e3 = row[p + 3];
            float n0 = rsqrtf(deg[e0.x]) * __int_as_float(e0.y) * dinv_d;
            float n1 = rsqrtf(deg[e1.x]) * __int_as_float(e1.y) * dinv_d;
            float n2 = rsqrtf(deg[e2.x]) * __int_as_float(e2.y) * dinv_d;
            float n3 = rsqrtf(deg[e3.x]) * __int_as_float(e3.y) * dinv_d;
            if constexpr (FPT == 8) {
                s8v v0 = *(const s8v*)&hb[(long long)e0.x * F + lane * 8];
                s8v v1 = *(const s8v*)&hb[(long long)e1.x * F + lane * 8];
                s8v v2 = *(const s8v*)&hb[(long long)e2.x * F + lane * 8];
                s8v v3 = *(const s8v*)&hb[(long long)e3.x * F + lane * 8];
#pragma unroll
                for (int j = 0; j < 8; j++)
                    acc[j] += n0 * bf2f(v0[j]) + n1 * bf2f(v1[j]) + n2 * bf2f(v2[j]) + n3 * bf2f(v3[j]);
            } else {
                s4v v0 = *(const s4v*)&hb[(long long)e0.x * F + lane * 4];
                s4v v1 = *(const s4v*)&hb[(long long)e1.x * F + lane * 4];
                s4v v2 = *(const s4v*)&hb[(long long)e2.x * F + lane * 4];
                s4v v3 = *(const s4v*)&hb[(long long)e3.x * F + lane * 4];
#pragma unroll
                for (int j = 0; j < 4; j++)
                    acc[j] += n0 * bf2f(v0[j]) + n1 * bf2f(v1[j]) + n2 * bf2f(v2[j]) + n3 * bf2f(v3[j]);
            }
        }
        for (; p < cnt; ++p) {
            int2 e0 = row[p];
            float n0 = rsqrtf(deg[e0.x]) * __int_as_float(e0.y) * dinv_d;
            if constexpr (FPT == 8) {
                s8v v0 = *(const s8v*)&hb[(long long)e0.x * F + lane * 8];
#pragma unroll
                for (int j = 0; j < 8; j++) acc[j] += n0 * bf2f(v0[j]);
            } else {
                s4v v0 = *(const s4v*)&hb[(long long)e0.x * F + lane * 4];
#pragma unroll
                for (int j = 0; j < 4; j++) acc[j] += n0 * bf2f(v0[j]);
            }
        }
        if (RELU) {
#pragma unroll
            for (int j = 0; j < FPT; j++) acc[j] = fmaxf(acc[j], 0.f);
        }
    }

    if constexpr (OUT_TILED) {  // F == 512: bf16 tiled+swizzled
        s8v v;
#pragma unroll
        for (int j = 0; j < 8; j++) v[j] = f2bf(acc[j]);
        int tm = wave >> 7, r = wave & 127, tk = lane >> 3, sc = lane & 7;
        int slot = sc ^ (r & 7);
        char* out = (char*)outp;
        *(s8v*)&out[(((long long)tm * KT + tk) << 14) + r * 128 + slot * 16] = v;
    } else {
        float* out = (float*)outp + (long long)wave * F + lane * FPT;
#pragma unroll
        for (int j = 0; j < FPT; j += 4) {
            *(float4*)&out[j] = make_float4(acc[j], acc[j + 1], acc[j + 2], acc[j + 3]);
        }
    }
}

// ---------------------------------------------------------------------------
extern "C" void kernel_launch(void* const* d_in, const int* in_sizes, int n_in,
                              void* d_out, int out_size, void* d_ws, size_t ws_size,
                              hipStream_t stream) {
    const float* x  = (const float*)d_in[0];                 // [10000, 512]
    const int*   ei = (const int*)d_in[1];                   // [2, 160000]
    const float* w  = (const float*)d_in[2];                 // [160000]
    const float* W1 = (const float*)d_in[3];                 // [512, 512]
    const float* W2 = (const float*)d_in[4];                 // [512, 256]
    float* out = (float*)d_out;                              // [10000, 256]

    const int* src = ei;
    const int* dst = ei + N_EDGES;

    char* p = (char*)d_ws;
    auto alloc = [&](size_t bytes) {
        char* r = p;
        p += (bytes + 255) & ~(size_t)255;
        return r;
    };
    char*  a1_bf  = alloc((size_t)MT * KT * 16384);
    char*  w1T    = alloc((size_t)4 * KT * 16384);
    char*  w2T    = alloc((size_t)2 * KT * 16384);
    short* h1_bf  = (short*)alloc((size_t)N_NODES * 512 * 2);
    short* h2_bf  = (short*)alloc((size_t)N_NODES * 256 * 2);
    float* deg    = (float*)alloc(N_NODES * 4);
    int*   count  = (int*)alloc(N_NODES * 4);
    int2*  ell    = (int2*)alloc((size_t)N_NODES * ELLW * 8);

    const int B = 256;

    // 1. prep: cvt_w1 + cvt_w2 + init deg/count (232 blocks, ~1.5 us)
    k_prep<<<232, B, 0, stream>>>(W1, W2, w1T, w2T, deg, count);
    // 2. layer-1 GEMM (inline x cvt, xcd-swizzled) + deg/ELL edge pass
    k_gemm1_deg<<<320 + 625, B, 0, stream>>>(x, w1T, h1_bf, src, dst, w, deg, count, ell);
    // 3. agg1 = relu(gather(h1)) -> tiled bf16 (pad rows zeroed)
    k_gather<512, true, true><<<(M_PAD * 64) / B, B, 0, stream>>>(
        ell, count, h1_bf, deg, a1_bf, M_PAD);
    // 4. layer-2 GEMM (128x64 tiles, xcd-swizzled)
    k_gemm2<<<320, B, 0, stream>>>(a1_bf, w2T, h2_bf);
    // 5. out = gather(h2) -> fp32
    k_gather<256, false, false><<<(N_NODES * 64) / B, B, 0, stream>>>(
        ell, count, h2_bf, deg, out, N_NODES);
}

// Round 10
// 88.306 us; speedup vs baseline: 1.1551x; 1.1551x over previous
//
#include <hip/hip_runtime.h>

#define N_NODES 10000
#define N_EDGES 160000
#define M_PAD   10112   // 79 * 128
#define MT      79
#define KT      8       // K = 512 = 8 * 64
#define ELLW    64      // max degree slot count (Poisson(16) tail @64 ~ 1e-18)

typedef short s8v __attribute__((ext_vector_type(8)));
typedef short s4v __attribute__((ext_vector_type(4)));
typedef float f4v __attribute__((ext_vector_type(4)));

__device__ inline short f2bf(float f) {
    unsigned u = __builtin_bit_cast(unsigned, f);
    u += 0x7FFF + ((u >> 16) & 1);   // RTNE
    return (short)(u >> 16);
}
__device__ inline float bf2f(short s) {
    return __builtin_bit_cast(float, ((unsigned)(unsigned short)s) << 16);
}

#define GLD_LDS16(g, l)                                                      \
    __builtin_amdgcn_global_load_lds(                                        \
        (const __attribute__((address_space(1))) unsigned int*)(g),          \
        (__attribute__((address_space(3))) unsigned int*)(l), 16, 0, 0)

// ---------------------------------------------------------------------------
// k_prep: fused independent prep, dispatched by blockIdx range.
//   [0, 2528)    : x fp32 -> bf16 tiled+swizzled
//   [2528, 2656) : W1^T -> bf16 tiled (512 cols)
//   [2656, 2720) : W2^T -> bf16 tiled (256 cols)
//   [2720, 2760) : deg = 1.0, count = 0
// Tile image = 16 KiB: [128 rows][64 k] bf16; chunk (r, slot) holds
// k = (slot ^ (r&7))*8 .. +8.  Buffer: [row_tile][k_tile][16384 B].
// ---------------------------------------------------------------------------
__global__ __launch_bounds__(256) void k_prep(const float* __restrict__ x,
                                              const float* __restrict__ W1,
                                              const float* __restrict__ W2,
                                              char* __restrict__ x_bf,
                                              char* __restrict__ w1T,
                                              char* __restrict__ w2T,
                                              float* __restrict__ deg,
                                              int* __restrict__ count) {
    int bid = blockIdx.x;
    if (bid < 2528) {
        long long t = (long long)bid * 256 + threadIdx.x;
        int gr = (int)(t >> 6);
        int c  = (int)(t & 63);
        s8v v;
        if (gr < N_NODES) {
            const float* p = &x[(long long)gr * 512 + c * 8];
#pragma unroll
            for (int j = 0; j < 8; j++) v[j] = f2bf(p[j]);
        } else {
#pragma unroll
            for (int j = 0; j < 8; j++) v[j] = 0;
        }
        int r = gr & 127, tm = gr >> 7, tk = c >> 3, sc = c & 7;
        int slot = sc ^ (r & 7);
        *(s8v*)&x_bf[(((long long)tm * KT + tk) << 14) + r * 128 + slot * 16] = v;
    } else if (bid < 2720) {
        const float* W;
        char* out;
        int ncols, t;
        if (bid < 2656) { W = W1; out = w1T; ncols = 512; t = (bid - 2528) * 256 + threadIdx.x; }
        else            { W = W2; out = w2T; ncols = 256; t = (bid - 2656) * 256 + threadIdx.x; }
        int n = t >> 6;
        int c = t & 63;
        s8v v;
#pragma unroll
        for (int j = 0; j < 8; j++) v[j] = f2bf(W[(long long)(c * 8 + j) * ncols + n]);
        int r = n & 127, tn = n >> 7, tk = c >> 3, sc = c & 7;
        int slot = sc ^ (r & 7);
        *(s8v*)&out[(((long long)tn * KT + tk) << 14) + r * 128 + slot * 16] = v;
    } else {
        int i = (bid - 2720) * 256 + threadIdx.x;
        if (i < N_NODES) { deg[i] = 1.0f; count[i] = 0; }
    }
}

// ---------------------------------------------------------------------------
// GEMM core (bf16 MFMA, 128x128 tile, BK=64, 4 waves 2x2, swizzled LDS).
// ---------------------------------------------------------------------------
__device__ __forceinline__ void gemm_block(const char* __restrict__ ga,
                                           const char* __restrict__ gb,
                                           short* __restrict__ Cb,
                                           int M, int N, int row_blk, int col_blk,
                                           char* As, char* Bs) {
    int tid = threadIdx.x, lane = tid & 63, w = tid >> 6;
    int wr = w >> 1, wc = w & 1;

    f4v acc[4][4];
#pragma unroll
    for (int m = 0; m < 4; m++)
#pragma unroll
        for (int n = 0; n < 4; n++) acc[m][n] = (f4v){0.f, 0.f, 0.f, 0.f};

    for (int kt = 0; kt < KT; ++kt) {
        const char* a0 = ga + (kt << 14);
        const char* b0 = gb + (kt << 14);
#pragma unroll
        for (int j = 0; j < 4; ++j) {
            int off = (j * 256 + w * 64) * 16;
            GLD_LDS16(a0 + off + lane * 16, As + off);
            GLD_LDS16(b0 + off + lane * 16, Bs + off);
        }
        __syncthreads();

#pragma unroll
        for (int kk = 0; kk < 2; ++kk) {
            s8v a[4], b[4];
#pragma unroll
            for (int m = 0; m < 4; ++m) {
                int r = wr * 64 + m * 16 + (lane & 15);
                int slot = ((lane >> 4) + kk * 4) ^ (r & 7);
                a[m] = *(const s8v*)&As[r * 128 + slot * 16];
            }
#pragma unroll
            for (int n = 0; n < 4; ++n) {
                int r = wc * 64 + n * 16 + (lane & 15);
                int slot = ((lane >> 4) + kk * 4) ^ (r & 7);
                b[n] = *(const s8v*)&Bs[r * 128 + slot * 16];
            }
#pragma unroll
            for (int m = 0; m < 4; ++m)
#pragma unroll
                for (int n = 0; n < 4; ++n)
                    acc[m][n] = __builtin_amdgcn_mfma_f32_16x16x32_bf16(a[m], b[n], acc[m][n], 0, 0, 0);
        }
        __syncthreads();
    }

    int row0 = row_blk * 128 + wr * 64;
    int col0 = col_blk * 128 + wc * 64;
#pragma unroll
    for (int m = 0; m < 4; ++m) {
#pragma unroll
        for (int q = 0; q < 4; ++q) {
            int row = row0 + m * 16 + (lane >> 4) * 4 + q;
            if (row < M) {
#pragma unroll
                for (int n = 0; n < 4; ++n) {
                    int col = col0 + n * 16 + (lane & 15);
                    Cb[(long long)row * N + col] = f2bf(acc[m][n][q]);
                }
            }
        }
    }
}

// layer-1 GEMM (316 blocks) + fused {deg accumulate, ELL fill} (625 blocks)
__global__ __launch_bounds__(256) void k_gemm1_deg(const char* __restrict__ A,
                                                   const char* __restrict__ B,
                                                   short* __restrict__ Cb,
                                                   const int* __restrict__ src,
                                                   const int* __restrict__ dst,
                                                   const float* __restrict__ wgt,
                                                   float* __restrict__ deg,
                                                   int* __restrict__ count,
                                                   int2* __restrict__ ell) {
    int bid = blockIdx.x;
    if (bid >= 316) {
        int e = (bid - 316) * 256 + threadIdx.x;
        if (e < N_EDGES) {
            int d = dst[e];
            float wv = wgt[e];
            atomicAdd(&deg[d], wv);
            int pos = atomicAdd(&count[d], 1);
            if (pos < ELLW)
                ell[(long long)d * ELLW + pos] = make_int2(src[e], __float_as_int(wv));
        }
        return;
    }
    __shared__ char As[16384];
    __shared__ char Bs[16384];
    int bx = bid & 3, by = bid >> 2;
    gemm_block(A + ((long long)by * KT << 14), B + ((long long)bx * KT << 14),
               Cb, N_NODES, 512, by, bx, As, Bs);
}

// ---------------------------------------------------------------------------
// XCD-chunked (by,bx) mapping over 320 virtual blocks (8 xcd x 10 by x 4 bx).
// ---------------------------------------------------------------------------
__device__ __forceinline__ void xcd_map(int b, int& by, int& bx) {
    by = (b & 7) * 10 + ((b >> 3) >> 2);
    bx = (b >> 3) & 3;
}

// ---------------------------------------------------------------------------
// layer-2 GEMM: 128(M) x 64(N) tile, A from tiled a1_bf images, B from w2T
// half-images (8 KiB). 4 waves as 2x2, wave tile 64x32. 320 blocks.
// ---------------------------------------------------------------------------
__global__ __launch_bounds__(256) void k_gemm2(const char* __restrict__ A,
                                               const char* __restrict__ w2T,
                                               short* __restrict__ Cb) {
    int by, bx;
    xcd_map(blockIdx.x, by, bx);
    if (by >= MT) return;

    __shared__ char As[16384];
    __shared__ char Bs[8192];
    int tid = threadIdx.x, lane = tid & 63, w = tid >> 6;
    int wr = w >> 1, wc = w & 1;

    const char* ga = A + ((long long)by * KT << 14);
    const char* gbase = w2T + ((long long)(bx >> 1) * KT << 14) + (bx & 1) * 8192;

    f4v acc[4][2];
#pragma unroll
    for (int m = 0; m < 4; m++)
#pragma unroll
        for (int n = 0; n < 2; n++) acc[m][n] = (f4v){0.f, 0.f, 0.f, 0.f};

    for (int kt = 0; kt < KT; ++kt) {
        const char* a0 = ga + (kt << 14);
        const char* b0 = gbase + (kt << 14);
#pragma unroll
        for (int j = 0; j < 4; ++j) {
            int off = (j * 256 + w * 64) * 16;
            GLD_LDS16(a0 + off + lane * 16, As + off);
        }
#pragma unroll
        for (int j = 0; j < 2; ++j) {
            int off = (j * 256 + w * 64) * 16;
            GLD_LDS16(b0 + off + lane * 16, Bs + off);
        }
        __syncthreads();

#pragma unroll
        for (int kk = 0; kk < 2; ++kk) {
            s8v a[4], b[2];
#pragma unroll
            for (int m = 0; m < 4; ++m) {
                int r = wr * 64 + m * 16 + (lane & 15);
                int slot = ((lane >> 4) + kk * 4) ^ (r & 7);
                a[m] = *(const s8v*)&As[r * 128 + slot * 16];
            }
#pragma unroll
            for (int n = 0; n < 2; ++n) {
                int r = wc * 32 + n * 16 + (lane & 15);
                int slot = ((lane >> 4) + kk * 4) ^ (r & 7);
                b[n] = *(const s8v*)&Bs[r * 128 + slot * 16];
            }
#pragma unroll
            for (int m = 0; m < 4; ++m)
#pragma unroll
                for (int n = 0; n < 2; ++n)
                    acc[m][n] = __builtin_amdgcn_mfma_f32_16x16x32_bf16(a[m], b[n], acc[m][n], 0, 0, 0);
        }
        __syncthreads();
    }

    int row0 = by * 128 + wr * 64;
    int col0 = bx * 64 + wc * 32;
#pragma unroll
    for (int m = 0; m < 4; ++m) {
#pragma unroll
        for (int q = 0; q < 4; ++q) {
            int row = row0 + m * 16 + (lane >> 4) * 4 + q;
            if (row < N_NODES) {
#pragma unroll
                for (int n = 0; n < 2; ++n) {
                    int col = col0 + n * 16 + (lane & 15);
                    Cb[(long long)row * 256 + col] = f2bf(acc[m][n][q]);
                }
            }
        }
    }
}

// ---------------------------------------------------------------------------
// ELL gather aggregation, bf16 input, norm computed in-flight.
// One wave per node, 8-edge unroll (MLP) + 4-edge + scalar tail.
// ---------------------------------------------------------------------------
template <int F, bool RELU, bool OUT_TILED>
__global__ __launch_bounds__(256) void k_gather(const int2* __restrict__ ell,
                                                const int* __restrict__ count,
                                                const short* __restrict__ hb,
                                                const float* __restrict__ deg,
                                                void* __restrict__ outp,
                                                int n_waves) {
    const int FPT = F / 64;  // 8 (F=512) or 4 (F=256)
    int wave = (int)((blockIdx.x * (long long)blockDim.x + threadIdx.x) >> 6);
    if (wave >= n_waves) return;
    int lane = threadIdx.x & 63;

    float acc[FPT];
#pragma unroll
    for (int j = 0; j < FPT; j++) acc[j] = 0.f;

    if (wave < N_NODES) {
        float dg = deg[wave];
        float inv = 1.0f / dg;
        float dinv_d = rsqrtf(dg);
        {
            if constexpr (FPT == 8) {
                s8v v = *(const s8v*)&hb[(long long)wave * F + lane * 8];
#pragma unroll
                for (int j = 0; j < 8; j++) acc[j] = bf2f(v[j]) * inv;
            } else {
                s4v v = *(const s4v*)&hb[(long long)wave * F + lane * 4];
#pragma unroll
                for (int j = 0; j < 4; j++) acc[j] = bf2f(v[j]) * inv;
            }
        }
        int cnt = count[wave];
        if (cnt > ELLW) cnt = ELLW;
        const int2* row = &ell[(long long)wave * ELLW];
        int p = 0;
        // ---- 8-edge unrolled main loop ----
        for (; p + 7 < cnt; p += 8) {
            int2 e[8];
#pragma unroll
            for (int q = 0; q < 8; q++) e[q] = row[p + q];
            float nn[8];
#pragma unroll
            for (int q = 0; q < 8; q++)
                nn[q] = rsqrtf(deg[e[q].x]) * __int_as_float(e[q].y) * dinv_d;
            if constexpr (FPT == 8) {
                s8v v[8];
#pragma unroll
                for (int q = 0; q < 8; q++)
                    v[q] = *(const s8v*)&hb[(long long)e[q].x * F + lane * 8];
#pragma unroll
                for (int j = 0; j < 8; j++) {
#pragma unroll
                    for (int q = 0; q < 8; q++) acc[j] += nn[q] * bf2f(v[q][j]);
                }
            } else {
                s4v v[8];
#pragma unroll
                for (int q = 0; q < 8; q++)
                    v[q] = *(const s4v*)&hb[(long long)e[q].x * F + lane * 4];
#pragma unroll
                for (int j = 0; j < 4; j++) {
#pragma unroll
                    for (int q = 0; q < 8; q++) acc[j] += nn[q] * bf2f(v[q][j]);
                }
            }
        }
        // ---- 4-edge tier ----
        for (; p + 3 < cnt; p += 4) {
            int2 e0 = row[p], e1 = row[p + 1], e2 = row[p + 2], e3 = row[p + 3];
            float n0 = rsqrtf(deg[e0.x]) * __int_as_float(e0.y) * dinv_d;
            float n1 = rsqrtf(deg[e1.x]) * __int_as_float(e1.y) * dinv_d;
            float n2 = rsqrtf(deg[e2.x]) * __int_as_float(e2.y) * dinv_d;
            float n3 = rsqrtf(deg[e3.x]) * __int_as_float(e3.y) * dinv_d;
            if constexpr (FPT == 8) {
                s8v v0 = *(const s8v*)&hb[(long long)e0.x * F + lane * 8];
                s8v v1 = *(const s8v*)&hb[(long long)e1.x * F + lane * 8];
                s8v v2 = *(const s8v*)&hb[(long long)e2.x * F + lane * 8];
                s8v v3 = *(const s8v*)&hb[(long long)e3.x * F + lane * 8];
#pragma unroll
                for (int j = 0; j < 8; j++)
                    acc[j] += n0 * bf2f(v0[j]) + n1 * bf2f(v1[j]) + n2 * bf2f(v2[j]) + n3 * bf2f(v3[j]);
            } else {
                s4v v0 = *(const s4v*)&hb[(long long)e0.x * F + lane * 4];
                s4v v1 = *(const s4v*)&hb[(long long)e1.x * F + lane * 4];
                s4v v2 = *(const s4v*)&hb[(long long)e2.x * F + lane * 4];
                s4v v3 = *(const s4v*)&hb[(long long)e3.x * F + lane * 4];
#pragma unroll
                for (int j = 0; j < 4; j++)
                    acc[j] += n0 * bf2f(v0[j]) + n1 * bf2f(v1[j]) + n2 * bf2f(v2[j]) + n3 * bf2f(v3[j]);
            }
        }
        // ---- scalar tail ----
        for (; p < cnt; ++p) {
            int2 e0 = row[p];
            float n0 = rsqrtf(deg[e0.x]) * __int_as_float(e0.y) * dinv_d;
            if constexpr (FPT == 8) {
                s8v v0 = *(const s8v*)&hb[(long long)e0.x * F + lane * 8];
#pragma unroll
                for (int j = 0; j < 8; j++) acc[j] += n0 * bf2f(v0[j]);
            } else {
                s4v v0 = *(const s4v*)&hb[(long long)e0.x * F + lane * 4];
#pragma unroll
                for (int j = 0; j < 4; j++) acc[j] += n0 * bf2f(v0[j]);
            }
        }
        if (RELU) {
#pragma unroll
            for (int j = 0; j < FPT; j++) acc[j] = fmaxf(acc[j], 0.f);
        }
    }

    if constexpr (OUT_TILED) {  // F == 512: bf16 tiled+swizzled
        s8v v;
#pragma unroll
        for (int j = 0; j < 8; j++) v[j] = f2bf(acc[j]);
        int tm = wave >> 7, r = wave & 127, tk = lane >> 3, sc = lane & 7;
        int slot = sc ^ (r & 7);
        char* out = (char*)outp;
        *(s8v*)&out[(((long long)tm * KT + tk) << 14) + r * 128 + slot * 16] = v;
    } else {
        float* out = (float*)outp + (long long)wave * F + lane * FPT;
#pragma unroll
        for (int j = 0; j < FPT; j += 4) {
            *(float4*)&out[j] = make_float4(acc[j], acc[j + 1], acc[j + 2], acc[j + 3]);
        }
    }
}

// ---------------------------------------------------------------------------
extern "C" void kernel_launch(void* const* d_in, const int* in_sizes, int n_in,
                              void* d_out, int out_size, void* d_ws, size_t ws_size,
                              hipStream_t stream) {
    const float* x  = (const float*)d_in[0];                 // [10000, 512]
    const int*   ei = (const int*)d_in[1];                   // [2, 160000]
    const float* w  = (const float*)d_in[2];                 // [160000]
    const float* W1 = (const float*)d_in[3];                 // [512, 512]
    const float* W2 = (const float*)d_in[4];                 // [512, 256]
    float* out = (float*)d_out;                              // [10000, 256]

    const int* src = ei;
    const int* dst = ei + N_EDGES;

    char* p = (char*)d_ws;
    auto alloc = [&](size_t bytes) {
        char* r = p;
        p += (bytes + 255) & ~(size_t)255;
        return r;
    };
    char*  x_bf   = alloc((size_t)MT * KT * 16384);
    char*  a1_bf  = alloc((size_t)MT * KT * 16384);
    char*  w1T    = alloc((size_t)4 * KT * 16384);
    char*  w2T    = alloc((size_t)2 * KT * 16384);
    short* h1_bf  = (short*)alloc((size_t)N_NODES * 512 * 2);
    short* h2_bf  = (short*)alloc((size_t)N_NODES * 256 * 2);
    float* deg    = (float*)alloc(N_NODES * 4);
    int*   count  = (int*)alloc(N_NODES * 4);
    int2*  ell    = (int2*)alloc((size_t)N_NODES * ELLW * 8);

    const int B = 256;

    // 1. fused prep: cvt_x + cvt_w1 + cvt_w2 + init deg/count
    k_prep<<<2760, B, 0, stream>>>(x, W1, W2, x_bf, w1T, w2T, deg, count);
    // 2. layer-1 GEMM (bf16 out) + deg accumulation + ELL fill
    k_gemm1_deg<<<316 + 625, B, 0, stream>>>(x_bf, w1T, h1_bf, src, dst, w, deg, count, ell);
    // 3. agg1 = relu(gather(h1)) -> tiled bf16 (pad rows zeroed)
    k_gather<512, true, true><<<(M_PAD * 64) / B, B, 0, stream>>>(
        ell, count, h1_bf, deg, a1_bf, M_PAD);
    // 4. layer-2 GEMM (128x64 tiles, 320 blocks, xcd-chunked)
    k_gemm2<<<320, B, 0, stream>>>(a1_bf, w2T, h2_bf);
    // 5. out = gather(h2) -> fp32
    k_gather<256, false, false><<<(N_NODES * 64) / B, B, 0, stream>>>(
        ell, count, h2_bf, deg, out, N_NODES);
}